// Round 1
// baseline (2165.526 us; speedup 1.0000x reference)
//
#include <hip/hip_runtime.h>
#include <math.h>

#define K_DIM 256
#define BJ 128      // queries per block
#define BI 128      // db rows per tile
#define KC 32       // K chunk staged in LDS
#define SD 36       // padded LDS row stride (floats): 2-way bank aliasing only

typedef unsigned long long u64;

// Monotone map fp32 -> u32 so unsigned compare == float compare.
__device__ __forceinline__ u64 packKey(float v, unsigned idx) {
    unsigned u = __float_as_uint(v);
    u = (u & 0x80000000u) ? ~u : (u | 0x80000000u);
    return ((u64)u << 32) | idx;
}
__device__ __forceinline__ float unpackVal(u64 k) {
    unsigned u = (unsigned)(k >> 32);
    u = (u & 0x80000000u) ? (u ^ 0x80000000u) : ~u;
    return __uint_as_float(u);
}

__global__ void init_kernel(u64* realKey, u64* genKey, float* out, int N, int M) {
    int t = blockIdx.x * blockDim.x + threadIdx.x;
    if (t < N) realKey[t] = ~0ull;
    if (t < M) genKey[t] = ~0ull;
    if (t == 0) out[0] = 0.f;
}

// One wave per row: 64 lanes x float4 = 256 elements.
__global__ void norms_kernel(const float* __restrict__ real, const float* __restrict__ gen,
                             float* __restrict__ rn, float* __restrict__ gn, int N, int M) {
    int wv = (blockIdx.x * blockDim.x + threadIdx.x) >> 6;
    int lane = threadIdx.x & 63;
    if (wv >= N + M) return;
    const float* src = (wv < N) ? (real + (size_t)wv * K_DIM)
                                : (gen + (size_t)(wv - N) * K_DIM);
    float4 v = ((const float4*)src)[lane];
    float s = v.x * v.x + v.y * v.y + v.z * v.z + v.w * v.w;
    #pragma unroll
    for (int off = 32; off > 0; off >>= 1) s += __shfl_down(s, off, 64);
    if (lane == 0) { if (wv < N) rn[wv] = s; else gn[wv - N] = s; }
}

// Fused GEMM + column-min(+argmin). blockIdx.z selects query matrix
// (0 = real w/ diagonal exclusion, 1 = gen). Min is over db rows (real).
__global__ __launch_bounds__(256) void nn_kernel(
    const float* __restrict__ real, const float* __restrict__ gen,
    const float* __restrict__ rn,
    u64* __restrict__ realKey, u64* __restrict__ genKey,
    int N, int M, int slices) {

    const bool isReal = (blockIdx.z == 0);
    const float* __restrict__ q = isReal ? real : gen;
    u64* outKey = isReal ? realKey : genKey;
    int qcount = isReal ? N : M;

    int j0 = blockIdx.x * BJ;
    if (j0 >= qcount) return;
    int rowsPerSlice = N / slices;
    int r0 = blockIdx.y * rowsPerSlice;
    int r1 = r0 + rowsPerSlice;

    __shared__ float dbt[BI * SD];
    __shared__ float qt[BJ * SD];
    __shared__ u64 red[BJ];

    int tid = threadIdx.x;
    int tx = tid & 15;   // db-row group
    int ty = tid >> 4;   // query group

    float minv[8];
    int mini[8];
    #pragma unroll
    for (int c = 0; c < 8; ++c) { minv[c] = 3.4e38f; mini[c] = 0; }

    for (int R = r0; R < r1; R += BI) {
        float acc[8][8];
        #pragma unroll
        for (int r = 0; r < 8; ++r)
            #pragma unroll
            for (int c = 0; c < 8; ++c) acc[r][c] = 0.f;

        for (int kc = 0; kc < K_DIM; kc += KC) {
            // Stage 128x32 db tile and 128x32 q tile (4 float4 each per thread).
            #pragma unroll
            for (int p = 0; p < 4; ++p) {
                int f = tid + p * 256;
                int i = f >> 3;            // row in tile
                int k4 = (f & 7) << 2;     // k offset
                float4 dv = *(const float4*)(real + (size_t)(R + i) * K_DIM + kc + k4);
                *(float4*)(dbt + i * SD + k4) = dv;
                float4 qv = *(const float4*)(q + (size_t)(j0 + i) * K_DIM + kc + k4);
                *(float4*)(qt + i * SD + k4) = qv;
            }
            __syncthreads();
            #pragma unroll
            for (int kk = 0; kk < KC; kk += 4) {
                float4 a[8], b[8];
                #pragma unroll
                for (int r = 0; r < 8; ++r)
                    a[r] = *(const float4*)(dbt + (tx + 16 * r) * SD + kk);
                #pragma unroll
                for (int c = 0; c < 8; ++c)
                    b[c] = *(const float4*)(qt + (ty + 16 * c) * SD + kk);
                #pragma unroll
                for (int r = 0; r < 8; ++r)
                    #pragma unroll
                    for (int c = 0; c < 8; ++c) {
                        acc[r][c] = fmaf(a[r].x, b[c].x, acc[r][c]);
                        acc[r][c] = fmaf(a[r].y, b[c].y, acc[r][c]);
                        acc[r][c] = fmaf(a[r].z, b[c].z, acc[r][c]);
                        acc[r][c] = fmaf(a[r].w, b[c].w, acc[r][c]);
                    }
            }
            __syncthreads();
        }

        // Epilogue: v = rn[i] - 2*dot  (qn[j] + sqrt deferred; monotone)
        float rnv[8];
        #pragma unroll
        for (int r = 0; r < 8; ++r) rnv[r] = rn[R + tx + 16 * r];
        #pragma unroll
        for (int c = 0; c < 8; ++c) {
            int jg = j0 + ty + 16 * c;
            #pragma unroll
            for (int r = 0; r < 8; ++r) {
                int ig = R + tx + 16 * r;
                float v = rnv[r] - 2.f * acc[r][c];
                bool skip = isReal && (ig == jg);
                if (!skip && v < minv[c]) { minv[c] = v; mini[c] = ig; }
            }
        }
    }

    // Block-level min reduce (packed u64 keeps argmin + first-index ties exact)
    if (tid < BJ) red[tid] = ~0ull;
    __syncthreads();
    #pragma unroll
    for (int c = 0; c < 8; ++c)
        atomicMin(&red[ty + 16 * c], packKey(minv[c], (unsigned)mini[c]));
    __syncthreads();
    if (tid < BJ) atomicMin(&outKey[j0 + tid], red[tid]);
}

__global__ void finalize_kernel(const u64* __restrict__ realKey, const u64* __restrict__ genKey,
                                const float* __restrict__ rn, const float* __restrict__ gn,
                                float* __restrict__ out, int M) {
    int j = blockIdx.x * blockDim.x + threadIdx.x;
    float a = 0.f;
    if (j < M) {
        u64 gk = genKey[j];
        float mg = unpackVal(gk);
        int idx = (int)(gk & 0xFFFFFFFFu);
        float d1 = sqrtf(fmaxf(mg + gn[j], 0.f));
        u64 rk = realKey[idx];
        float d2 = sqrtf(fmaxf(unpackVal(rk) + rn[idx], 0.f));
        float z = (d2 - d1) * 10.f;   // / TEMP
        a = 1.f / (1.f + expf(-z));
    }
    #pragma unroll
    for (int off = 32; off > 0; off >>= 1) a += __shfl_down(a, off, 64);
    __shared__ float sred[4];
    int lane = threadIdx.x & 63, wv = threadIdx.x >> 6;
    if (lane == 0) sred[wv] = a;
    __syncthreads();
    if (threadIdx.x == 0) {
        float s = sred[0] + sred[1] + sred[2] + sred[3];
        atomicAdd(out, s * (-100.f / (float)M));
    }
}

extern "C" void kernel_launch(void* const* d_in, const int* in_sizes, int n_in,
                              void* d_out, int out_size, void* d_ws, size_t ws_size,
                              hipStream_t stream) {
    const float* real = (const float*)d_in[0];
    const float* gen  = (const float*)d_in[1];
    float* out = (float*)d_out;
    int N = in_sizes[0] / K_DIM;
    int M = in_sizes[1] / K_DIM;

    u64* realKey = (u64*)d_ws;
    u64* genKey  = realKey + N;
    float* rn = (float*)(genKey + M);
    float* gn = rn + N;

    const int S = 4;  // db slices -> (96,4,2) = 768 blocks ~ 3/CU

    int mx = (N > M ? N : M);
    init_kernel<<<(mx + 255) / 256, 256, 0, stream>>>(realKey, genKey, out, N, M);
    norms_kernel<<<(N + M + 3) / 4, 256, 0, stream>>>(real, gen, rn, gn, N, M);
    dim3 g((mx + BJ - 1) / BJ, S, 2);
    nn_kernel<<<g, 256, 0, stream>>>(real, gen, rn, realKey, genKey, N, M, S);
    finalize_kernel<<<(M + 255) / 256, 256, 0, stream>>>(realKey, genKey, rn, gn, out, M);
}

// Round 2
// 370.615 us; speedup vs baseline: 5.8431x; 5.8431x over previous
//
#include <hip/hip_runtime.h>
#include <math.h>

#define K_DIM 256
#define BJ 128      // queries per block tile
#define BI 128      // db rows per tile
#define KC 32       // bf16 K-chunk staged in LDS (one 16x16x32 MFMA step)

typedef unsigned long long u64;
typedef __attribute__((ext_vector_type(8))) short bf16x8;   // MFMA A/B frag (4 VGPR)
typedef __attribute__((ext_vector_type(4))) float f32x4;    // MFMA C/D frag

// Monotone map fp32 -> u32 so unsigned compare == float compare.
__device__ __forceinline__ u64 packKey(float v, unsigned idx) {
    unsigned u = __float_as_uint(v);
    u = (u & 0x80000000u) ? ~u : (u | 0x80000000u);
    return ((u64)u << 32) | idx;
}
__device__ __forceinline__ float unpackVal(u64 k) {
    unsigned u = (unsigned)(k >> 32);
    u = (u & 0x80000000u) ? (u ^ 0x80000000u) : ~u;
    return __uint_as_float(u);
}

__device__ __forceinline__ unsigned short f2bf(float x) {   // RNE fp32->bf16
    unsigned u = __float_as_uint(x);
    return (unsigned short)((u + 0x7FFFu + ((u >> 16) & 1u)) >> 16);
}
__device__ __forceinline__ float bf2f(unsigned short b) {
    return __uint_as_float((unsigned)b << 16);
}

__global__ void init_kernel(u64* realKey, u64* genKey, float* out, int N, int M) {
    int t = blockIdx.x * blockDim.x + threadIdx.x;
    if (t < N) realKey[t] = ~0ull;
    if (t < M) genKey[t] = ~0ull;
    if (t == 0) out[0] = 0.f;
}

// One wave per row: quantize fp32->bf16 AND compute the norm of the QUANTIZED
// vector (keeps rn/gn exactly consistent with the bf16 MFMA dot products).
__global__ void convert_kernel(const float* __restrict__ real, const float* __restrict__ gen,
                               short* __restrict__ realb, short* __restrict__ genb,
                               float* __restrict__ rn, float* __restrict__ gn, int N, int M) {
    int wv = (blockIdx.x * blockDim.x + threadIdx.x) >> 6;
    int lane = threadIdx.x & 63;
    if (wv >= N + M) return;
    const float* src;
    short* dst;
    if (wv < N) { src = real + (size_t)wv * K_DIM; dst = realb + (size_t)wv * K_DIM; }
    else        { src = gen + (size_t)(wv - N) * K_DIM; dst = genb + (size_t)(wv - N) * K_DIM; }
    float4 v = ((const float4*)src)[lane];
    ushort4 b;
    b.x = f2bf(v.x); b.y = f2bf(v.y); b.z = f2bf(v.z); b.w = f2bf(v.w);
    float qx = bf2f(b.x), qy = bf2f(b.y), qz = bf2f(b.z), qw = bf2f(b.w);
    float s = qx * qx + qy * qy + qz * qz + qw * qw;
    ((ushort4*)dst)[lane] = b;
    #pragma unroll
    for (int off = 32; off > 0; off >>= 1) s += __shfl_down(s, off, 64);
    if (lane == 0) { if (wv < N) rn[wv] = s; else gn[wv - N] = s; }
}

// Fused bf16-MFMA GEMM + column-min(+argmin). blockIdx.z: 0 = real queries
// (diagonal excluded), 1 = gen queries. Min is over db rows (real).
// m97 structure: 128x128 tile, 4 waves x (64x64 = 4x4 frags of 16x16x32),
// BK=32 staged with global_load_lds width=16, unpadded row-major LDS.
__global__ __launch_bounds__(256) void nn_kernel(
    const short* __restrict__ realb, const short* __restrict__ genb,
    const float* __restrict__ rn,
    u64* __restrict__ realKey, u64* __restrict__ genKey,
    int N, int M, int slices) {

    const bool isReal = (blockIdx.z == 0);
    const short* __restrict__ q = isReal ? realb : genb;
    u64* outKey = isReal ? realKey : genKey;

    const int j0 = blockIdx.x * BJ;
    const int rowsPerSlice = N / slices;
    const int r0 = blockIdx.y * rowsPerSlice;
    const int r1 = r0 + rowsPerSlice;

    __shared__ short At[BI * KC];   // 8 KB, [i][k] row-major, NO pad (global_load_lds)
    __shared__ short Bt[BJ * KC];   // 8 KB, [j][k] row-major
    __shared__ u64 red[BJ];

    const int tid = threadIdx.x;
    const int lane = tid & 63;
    const int w = tid >> 6;
    const int wi = w >> 1;          // wave's 64-row block (i)
    const int wj = w & 1;           // wave's 64-col block (j)
    const int quad = lane >> 4;
    const int col = lane & 15;

    if (tid < BJ) red[tid] = ~0ull;

    for (int R = r0; R < r1; R += BI) {
        f32x4 acc[4][4];
        #pragma unroll
        for (int mi = 0; mi < 4; ++mi)
            #pragma unroll
            for (int ni = 0; ni < 4; ++ni)
                acc[mi][ni] = (f32x4){0.f, 0.f, 0.f, 0.f};

        for (int kc = 0; kc < K_DIM; kc += KC) {
            // Stage A (db rows) and B (query rows): 2 x 16B issues each per thread.
            #pragma unroll
            for (int p = 0; p < 2; ++p) {
                int f = p * 256 + tid;
                int row = f >> 2;
                int ko = (f & 3) << 3;
                __builtin_amdgcn_global_load_lds(
                    (const __attribute__((address_space(1))) void*)(realb + (size_t)(R + row) * K_DIM + kc + ko),
                    (__attribute__((address_space(3))) void*)(At + ((f & ~63) << 3)),
                    16, 0, 0);
                __builtin_amdgcn_global_load_lds(
                    (const __attribute__((address_space(1))) void*)(q + (size_t)(j0 + row) * K_DIM + kc + ko),
                    (__attribute__((address_space(3))) void*)(Bt + ((f & ~63) << 3)),
                    16, 0, 0);
            }
            __syncthreads();

            bf16x8 a[4], b[4];
            #pragma unroll
            for (int mi = 0; mi < 4; ++mi)
                a[mi] = *(const bf16x8*)(At + (wi * 64 + mi * 16 + col) * KC + quad * 8);
            #pragma unroll
            for (int ni = 0; ni < 4; ++ni)
                b[ni] = *(const bf16x8*)(Bt + (wj * 64 + ni * 16 + col) * KC + quad * 8);
            #pragma unroll
            for (int mi = 0; mi < 4; ++mi)
                #pragma unroll
                for (int ni = 0; ni < 4; ++ni)
                    acc[mi][ni] = __builtin_amdgcn_mfma_f32_16x16x32_bf16(a[mi], b[ni], acc[mi][ni], 0, 0, 0);
            __syncthreads();
        }

        // Epilogue: v = rn[i] - 2*dot   (qn[j] + sqrt deferred; monotone in i).
        // C/D layout: col = lane&15 (j), row = quad*4 + reg (i).
        float rnv[16];
        #pragma unroll
        for (int mi = 0; mi < 4; ++mi)
            #pragma unroll
            for (int r = 0; r < 4; ++r)
                rnv[mi * 4 + r] = rn[R + wi * 64 + mi * 16 + quad * 4 + r];

        #pragma unroll
        for (int ni = 0; ni < 4; ++ni) {
            int jl = wj * 64 + ni * 16 + col;
            int jg = j0 + jl;
            float mv = 3.4e38f;
            int miIdx = 0;
            #pragma unroll
            for (int mi = 0; mi < 4; ++mi)
                #pragma unroll
                for (int r = 0; r < 4; ++r) {
                    int ig = R + wi * 64 + mi * 16 + quad * 4 + r;
                    float v = rnv[mi * 4 + r] - 2.f * acc[mi][ni][r];
                    bool skip = isReal && (ig == jg);
                    if (!skip && v < mv) { mv = v; miIdx = ig; }
                }
            atomicMin(&red[jl], packKey(mv, (unsigned)miIdx));
        }
    }

    __syncthreads();
    if (tid < BJ) atomicMin(&outKey[j0 + tid], red[tid]);
}

__global__ void finalize_kernel(const u64* __restrict__ realKey, const u64* __restrict__ genKey,
                                const float* __restrict__ rn, const float* __restrict__ gn,
                                float* __restrict__ out, int M) {
    int j = blockIdx.x * blockDim.x + threadIdx.x;
    float a = 0.f;
    if (j < M) {
        u64 gk = genKey[j];
        float mg = unpackVal(gk);
        int idx = (int)(gk & 0xFFFFFFFFu);
        float d1 = sqrtf(fmaxf(mg + gn[j], 0.f));
        u64 rk = realKey[idx];
        float d2 = sqrtf(fmaxf(unpackVal(rk) + rn[idx], 0.f));
        float z = (d2 - d1) * 10.f;   // / TEMP
        a = 1.f / (1.f + expf(-z));
    }
    #pragma unroll
    for (int off = 32; off > 0; off >>= 1) a += __shfl_down(a, off, 64);
    __shared__ float sred[4];
    int lane = threadIdx.x & 63, wv = threadIdx.x >> 6;
    if (lane == 0) sred[wv] = a;
    __syncthreads();
    if (threadIdx.x == 0) {
        float s = sred[0] + sred[1] + sred[2] + sred[3];
        atomicAdd(out, s * (-100.f / (float)M));
    }
}

extern "C" void kernel_launch(void* const* d_in, const int* in_sizes, int n_in,
                              void* d_out, int out_size, void* d_ws, size_t ws_size,
                              hipStream_t stream) {
    const float* real = (const float*)d_in[0];
    const float* gen  = (const float*)d_in[1];
    float* out = (float*)d_out;
    int N = in_sizes[0] / K_DIM;
    int M = in_sizes[1] / K_DIM;

    // Workspace layout (≈12.9 MB total):
    u64* realKey = (u64*)d_ws;
    u64* genKey  = realKey + N;
    float* rn = (float*)(genKey + M);
    float* gn = rn + N;
    short* realb = (short*)(gn + M);
    short* genb  = realb + (size_t)N * K_DIM;

    const int S = 4;   // db slices: grid (96, 4, 2) = 768 blocks = 3/CU

    int mx = (N > M ? N : M);
    init_kernel<<<(mx + 255) / 256, 256, 0, stream>>>(realKey, genKey, out, N, M);
    convert_kernel<<<(N + M + 3) / 4, 256, 0, stream>>>(real, gen, realb, genb, rn, gn, N, M);
    dim3 g((mx + BJ - 1) / BJ, S, 2);
    nn_kernel<<<g, 256, 0, stream>>>(realb, genb, rn, realKey, genKey, N, M, S);
    finalize_kernel<<<(M + 255) / 256, 256, 0, stream>>>(realKey, genKey, rn, gn, out, M);
}

// Round 3
// 310.858 us; speedup vs baseline: 6.9663x; 1.1922x over previous
//
#include <hip/hip_runtime.h>
#include <math.h>

#define K_DIM 256
#define BJ 128      // queries per block tile
#define BI 128      // db rows per tile
#define KC 32       // bf16 K-chunk staged in LDS (one 16x16x32 MFMA step)
#define SLICES 16   // grid (96,16,2)=3072 blocks = 12/CU = 3 rounds of 4 resident

typedef unsigned long long u64;
typedef __attribute__((ext_vector_type(8))) short bf16x8;   // MFMA A/B frag (4 VGPR)
typedef __attribute__((ext_vector_type(4))) float f32x4;    // MFMA C/D frag

// Monotone map fp32 -> u32 so unsigned compare == float compare.
__device__ __forceinline__ u64 packKey(float v, unsigned idx) {
    unsigned u = __float_as_uint(v);
    u = (u & 0x80000000u) ? ~u : (u | 0x80000000u);
    return ((u64)u << 32) | idx;
}
__device__ __forceinline__ float unpackVal(u64 k) {
    unsigned u = (unsigned)(k >> 32);
    u = (u & 0x80000000u) ? (u ^ 0x80000000u) : ~u;
    return __uint_as_float(u);
}
__device__ __forceinline__ u64 shfl_xor_u64(u64 x, int m) {
    unsigned lo = (unsigned)x, hi = (unsigned)(x >> 32);
    lo = __shfl_xor(lo, m, 64);
    hi = __shfl_xor(hi, m, 64);
    return ((u64)hi << 32) | lo;
}

__device__ __forceinline__ unsigned short f2bf(float x) {   // RNE fp32->bf16
    unsigned u = __float_as_uint(x);
    return (unsigned short)((u + 0x7FFFu + ((u >> 16) & 1u)) >> 16);
}
__device__ __forceinline__ float bf2f(unsigned short b) {
    return __uint_as_float((unsigned)b << 16);
}

__global__ void init_kernel(u64* realKey, u64* genKey, float* out, int N, int M) {
    int t = blockIdx.x * blockDim.x + threadIdx.x;
    if (t < N) realKey[t] = ~0ull;
    if (t < M) genKey[t] = ~0ull;
    if (t == 0) out[0] = 0.f;
}

// One wave per row: quantize fp32->bf16 AND compute the norm of the QUANTIZED
// vector (keeps rn/gn exactly consistent with the bf16 MFMA dot products).
__global__ void convert_kernel(const float* __restrict__ real, const float* __restrict__ gen,
                               short* __restrict__ realb, short* __restrict__ genb,
                               float* __restrict__ rn, float* __restrict__ gn, int N, int M) {
    int wv = (blockIdx.x * blockDim.x + threadIdx.x) >> 6;
    int lane = threadIdx.x & 63;
    if (wv >= N + M) return;
    const float* src;
    short* dst;
    if (wv < N) { src = real + (size_t)wv * K_DIM; dst = realb + (size_t)wv * K_DIM; }
    else        { src = gen + (size_t)(wv - N) * K_DIM; dst = genb + (size_t)(wv - N) * K_DIM; }
    float4 v = ((const float4*)src)[lane];
    ushort4 b;
    b.x = f2bf(v.x); b.y = f2bf(v.y); b.z = f2bf(v.z); b.w = f2bf(v.w);
    float qx = bf2f(b.x), qy = bf2f(b.y), qz = bf2f(b.z), qw = bf2f(b.w);
    float s = qx * qx + qy * qy + qz * qz + qw * qw;
    ((ushort4*)dst)[lane] = b;
    #pragma unroll
    for (int off = 32; off > 0; off >>= 1) s += __shfl_down(s, off, 64);
    if (lane == 0) { if (wv < N) rn[wv] = s; else gn[wv - N] = s; }
}

// Fused bf16-MFMA GEMM + column-min(+argmin). blockIdx.z: 0 = real queries
// (diagonal excluded), 1 = gen queries. Min is over db rows (real).
// 128x128 tile, 4 waves x (64x64 = 4x4 frags of 16x16x32), BK=32 staged with
// global_load_lds width=16. LDS 16B-chunk placement is rotate-swizzled by
// (row>>1) so frag reads are 2-way bank aliased (free) instead of 8-way:
// phys_chunk = (logical_quad + (row>>1)) & 3, applied on the GLOBAL source
// side (the LDS dest of global_load_lds is fixed wave-uniform+lane*16).
__global__ __launch_bounds__(256) void nn_kernel(
    const short* __restrict__ realb, const short* __restrict__ genb,
    const float* __restrict__ rn,
    u64* __restrict__ realKey, u64* __restrict__ genKey,
    int N, int M, int slices) {

    const bool isReal = (blockIdx.z == 0);
    const short* __restrict__ q = isReal ? realb : genb;
    u64* outKey = isReal ? realKey : genKey;

    const int j0 = blockIdx.x * BJ;
    const int rowsPerSlice = N / slices;
    const int r0 = blockIdx.y * rowsPerSlice;
    const int r1 = r0 + rowsPerSlice;

    __shared__ short At[BI * KC];   // 8 KB, [i][chunk-swizzled k]
    __shared__ short Bt[BJ * KC];   // 8 KB
    __shared__ u64 red[BJ];

    const int tid = threadIdx.x;
    const int lane = tid & 63;
    const int w = tid >> 6;
    const int wi = w >> 1;          // wave's 64-row block (i)
    const int wj = w & 1;           // wave's 64-col block (j)
    const int quad = lane >> 4;
    const int col = lane & 15;

    if (tid < BJ) red[tid] = ~0ull;

    for (int R = r0; R < r1; R += BI) {
        f32x4 acc[4][4];
        #pragma unroll
        for (int mi = 0; mi < 4; ++mi)
            #pragma unroll
            for (int ni = 0; ni < 4; ++ni)
                acc[mi][ni] = (f32x4){0.f, 0.f, 0.f, 0.f};

        for (int kc = 0; kc < K_DIM; kc += KC) {
            // Stage A (db rows) and B (query rows): 2 x 16B issues each per
            // thread; global source chunk permuted per the swizzle.
            #pragma unroll
            for (int p = 0; p < 2; ++p) {
                int f = p * 256 + tid;
                int row = f >> 2;
                int s = f & 3;                       // physical 16B chunk
                int qk = (s - (row >> 1)) & 3;       // logical chunk fetched
                __builtin_amdgcn_global_load_lds(
                    (const __attribute__((address_space(1))) void*)(realb + (size_t)(R + row) * K_DIM + kc + qk * 8),
                    (__attribute__((address_space(3))) void*)(At + ((f & ~63) << 3)),
                    16, 0, 0);
                __builtin_amdgcn_global_load_lds(
                    (const __attribute__((address_space(1))) void*)(q + (size_t)(j0 + row) * K_DIM + kc + qk * 8),
                    (__attribute__((address_space(3))) void*)(Bt + ((f & ~63) << 3)),
                    16, 0, 0);
            }
            __syncthreads();

            bf16x8 a[4], b[4];
            #pragma unroll
            for (int mi = 0; mi < 4; ++mi) {
                int i = wi * 64 + mi * 16 + col;
                a[mi] = *(const bf16x8*)(At + i * KC + (((quad + (i >> 1)) & 3) << 3));
            }
            #pragma unroll
            for (int ni = 0; ni < 4; ++ni) {
                int i = wj * 64 + ni * 16 + col;
                b[ni] = *(const bf16x8*)(Bt + i * KC + (((quad + (i >> 1)) & 3) << 3));
            }
            #pragma unroll
            for (int mi = 0; mi < 4; ++mi)
                #pragma unroll
                for (int ni = 0; ni < 4; ++ni)
                    acc[mi][ni] = __builtin_amdgcn_mfma_f32_16x16x32_bf16(a[mi], b[ni], acc[mi][ni], 0, 0, 0);
            __syncthreads();
        }

        // Epilogue: v = rn[i] - 2*dot   (qn[j] + sqrt deferred; monotone).
        // C/D layout: col = lane&15 (j), row = quad*4 + reg (i).
        float4 rnv4[4];
        #pragma unroll
        for (int mi = 0; mi < 4; ++mi)
            rnv4[mi] = *(const float4*)(rn + R + wi * 64 + mi * 16 + quad * 4);

        #pragma unroll
        for (int ni = 0; ni < 4; ++ni) {
            int jl = wj * 64 + ni * 16 + col;
            int jg = j0 + jl;
            float mv = 3.4e38f;
            int miIdx = 0;
            #pragma unroll
            for (int mi = 0; mi < 4; ++mi)
                #pragma unroll
                for (int r = 0; r < 4; ++r) {
                    int ig = R + wi * 64 + mi * 16 + quad * 4 + r;
                    float v = (&rnv4[mi].x)[r] - 2.f * acc[mi][ni][r];
                    bool skip = isReal && (ig == jg);
                    if (!skip && v < mv) { mv = v; miIdx = ig; }
                }
            // Lanes +-16/+-32 hold the same query column: reduce across quads
            // in-register, then only quad 0 touches the LDS atomic.
            u64 k = packKey(mv, (unsigned)miIdx);
            u64 o = shfl_xor_u64(k, 16); if (o < k) k = o;
            o = shfl_xor_u64(k, 32); if (o < k) k = o;
            if (quad == 0) atomicMin(&red[jl], k);
        }
    }

    __syncthreads();
    if (tid < BJ) atomicMin(&outKey[j0 + tid], red[tid]);
}

__global__ void finalize_kernel(const u64* __restrict__ realKey, const u64* __restrict__ genKey,
                                const float* __restrict__ rn, const float* __restrict__ gn,
                                float* __restrict__ out, int M) {
    int j = blockIdx.x * blockDim.x + threadIdx.x;
    float a = 0.f;
    if (j < M) {
        u64 gk = genKey[j];
        float mg = unpackVal(gk);
        int idx = (int)(gk & 0xFFFFFFFFu);
        float d1 = sqrtf(fmaxf(mg + gn[j], 0.f));
        u64 rk = realKey[idx];
        float d2 = sqrtf(fmaxf(unpackVal(rk) + rn[idx], 0.f));
        float z = (d2 - d1) * 10.f;   // / TEMP
        a = 1.f / (1.f + expf(-z));
    }
    #pragma unroll
    for (int off = 32; off > 0; off >>= 1) a += __shfl_down(a, off, 64);
    __shared__ float sred[4];
    int lane = threadIdx.x & 63, wv = threadIdx.x >> 6;
    if (lane == 0) sred[wv] = a;
    __syncthreads();
    if (threadIdx.x == 0) {
        float s = sred[0] + sred[1] + sred[2] + sred[3];
        atomicAdd(out, s * (-100.f / (float)M));
    }
}

extern "C" void kernel_launch(void* const* d_in, const int* in_sizes, int n_in,
                              void* d_out, int out_size, void* d_ws, size_t ws_size,
                              hipStream_t stream) {
    const float* real = (const float*)d_in[0];
    const float* gen  = (const float*)d_in[1];
    float* out = (float*)d_out;
    int N = in_sizes[0] / K_DIM;
    int M = in_sizes[1] / K_DIM;

    // Workspace layout (~12.9 MB total):
    u64* realKey = (u64*)d_ws;
    u64* genKey  = realKey + N;
    float* rn = (float*)(genKey + M);
    float* gn = rn + N;
    short* realb = (short*)(gn + M);
    short* genb  = realb + (size_t)N * K_DIM;

    int mx = (N > M ? N : M);
    init_kernel<<<(mx + 255) / 256, 256, 0, stream>>>(realKey, genKey, out, N, M);
    convert_kernel<<<(N + M + 3) / 4, 256, 0, stream>>>(real, gen, realb, genb, rn, gn, N, M);
    dim3 g((mx + BJ - 1) / BJ, SLICES, 2);
    nn_kernel<<<g, 256, 0, stream>>>(realb, genb, rn, realKey, genKey, N, M, SLICES);
    finalize_kernel<<<(M + 255) / 256, 256, 0, stream>>>(realKey, genKey, rn, gn, out, M);
}

// Round 4
// 284.819 us; speedup vs baseline: 7.6032x; 1.0914x over previous
//
#include <hip/hip_runtime.h>
#include <math.h>

#define K_DIM 256
#define BJ 128      // queries per block tile
#define BI 128      // db rows per tile
#define KC 32       // bf16 K-chunk staged in LDS (one 16x16x32 MFMA step)
#define SLICES 16   // grid (96,16,2)=3072 blocks of 512 thr = 6 rounds of 2/CU

typedef unsigned long long u64;
typedef __attribute__((ext_vector_type(8))) short bf16x8;   // MFMA A/B frag (4 VGPR)
typedef __attribute__((ext_vector_type(4))) float f32x4;    // MFMA C/D frag

// Monotone map fp32 -> u32 so unsigned compare == float compare.
__device__ __forceinline__ u64 packKey(float v, unsigned idx) {
    unsigned u = __float_as_uint(v);
    u = (u & 0x80000000u) ? ~u : (u | 0x80000000u);
    return ((u64)u << 32) | idx;
}
__device__ __forceinline__ float unpackVal(u64 k) {
    unsigned u = (unsigned)(k >> 32);
    u = (u & 0x80000000u) ? (u ^ 0x80000000u) : ~u;
    return __uint_as_float(u);
}
__device__ __forceinline__ u64 shfl_xor_u64(u64 x, int m) {
    unsigned lo = (unsigned)x, hi = (unsigned)(x >> 32);
    lo = __shfl_xor(lo, m, 64);
    hi = __shfl_xor(hi, m, 64);
    return ((u64)hi << 32) | lo;
}

__device__ __forceinline__ unsigned short f2bf(float x) {   // RNE fp32->bf16
    unsigned u = __float_as_uint(x);
    return (unsigned short)((u + 0x7FFFu + ((u >> 16) & 1u)) >> 16);
}
__device__ __forceinline__ float bf2f(unsigned short b) {
    return __uint_as_float((unsigned)b << 16);
}

__global__ void init_kernel(u64* realKey, u64* genKey, float* out, int N, int M) {
    int t = blockIdx.x * blockDim.x + threadIdx.x;
    if (t < N) realKey[t] = ~0ull;
    if (t < M) genKey[t] = ~0ull;
    if (t == 0) out[0] = 0.f;
}

// One wave per row: quantize fp32->bf16 AND compute the norm of the QUANTIZED
// vector (keeps rn/gn exactly consistent with the bf16 MFMA dot products).
__global__ void convert_kernel(const float* __restrict__ real, const float* __restrict__ gen,
                               short* __restrict__ realb, short* __restrict__ genb,
                               float* __restrict__ rn, float* __restrict__ gn, int N, int M) {
    int wv = (blockIdx.x * blockDim.x + threadIdx.x) >> 6;
    int lane = threadIdx.x & 63;
    if (wv >= N + M) return;
    const float* src;
    short* dst;
    if (wv < N) { src = real + (size_t)wv * K_DIM; dst = realb + (size_t)wv * K_DIM; }
    else        { src = gen + (size_t)(wv - N) * K_DIM; dst = genb + (size_t)(wv - N) * K_DIM; }
    float4 v = ((const float4*)src)[lane];
    ushort4 b;
    b.x = f2bf(v.x); b.y = f2bf(v.y); b.z = f2bf(v.z); b.w = f2bf(v.w);
    float qx = bf2f(b.x), qy = bf2f(b.y), qz = bf2f(b.z), qw = bf2f(b.w);
    float s = qx * qx + qy * qy + qz * qz + qw * qw;
    ((ushort4*)dst)[lane] = b;
    #pragma unroll
    for (int off = 32; off > 0; off >>= 1) s += __shfl_down(s, off, 64);
    if (lane == 0) { if (wv < N) rn[wv] = s; else gn[wv - N] = s; }
}

// Fused bf16-MFMA GEMM + column-min(+argmin). blockIdx.z: 0 = real queries
// (diagonal excluded), 1 = gen queries. Min is over db rows (real).
// 512 threads = 8 waves, each owning a 32x64 sub-tile (2x4 frags, 32 acc
// VGPRs) of the 128x128 block tile -> <=128 VGPR/wave -> 4 waves/SIMD.
// BK=32 staged with global_load_lds width=16 (1 A + 1 B issue per thread).
// LDS 16B-chunk placement rotate-swizzled by (row>>1): frag reads 2-way
// bank aliased (free). Running min kept in registers across R-tiles;
// pack/shfl/atomic reduction happens ONCE per block.
__global__ __launch_bounds__(512, 4) void nn_kernel(
    const short* __restrict__ realb, const short* __restrict__ genb,
    const float* __restrict__ rn,
    u64* __restrict__ realKey, u64* __restrict__ genKey,
    int N, int M, int slices) {

    const bool isReal = (blockIdx.z == 0);
    const short* __restrict__ q = isReal ? realb : genb;
    u64* outKey = isReal ? realKey : genKey;

    const int j0 = blockIdx.x * BJ;
    const int rowsPerSlice = N / slices;
    const int r0 = blockIdx.y * rowsPerSlice;
    const int r1 = r0 + rowsPerSlice;

    __shared__ short At[BI * KC];   // 8 KB, [i][chunk-swizzled k]
    __shared__ short Bt[BJ * KC];   // 8 KB
    __shared__ u64 red[BJ];

    const int tid = threadIdx.x;
    const int lane = tid & 63;
    const int w = tid >> 6;         // 0..7
    const int wi = w >> 1;          // wave's 32-row block (i): 0..3
    const int wj = w & 1;           // wave's 64-col block (j): 0..1
    const int quad = lane >> 4;
    const int col = lane & 15;

    // Staging coords: 4 threads per 64B row, 1 x 16B issue per buffer.
    const int srow = tid >> 2;            // 0..127
    const int schunk = tid & 3;           // physical 16B chunk
    const int sqk = (schunk - (srow >> 1)) & 3;  // logical chunk fetched
    const short* aSrc0 = realb + (size_t)(r0 + srow) * K_DIM + sqk * 8;
    const short* bSrc0 = q + (size_t)(j0 + srow) * K_DIM + sqk * 8;
    const int ldsOff = (tid & ~63) << 3;  // wave-uniform dest (shorts)

    if (tid < BJ) red[tid] = ~0ull;

    float minv[4];
    int mini[4];
    #pragma unroll
    for (int ni = 0; ni < 4; ++ni) { minv[ni] = 3.4e38f; mini[ni] = 0; }

    for (int R = r0; R < r1; R += BI) {
        f32x4 acc[2][4];
        #pragma unroll
        for (int mi = 0; mi < 2; ++mi)
            #pragma unroll
            for (int ni = 0; ni < 4; ++ni)
                acc[mi][ni] = (f32x4){0.f, 0.f, 0.f, 0.f};

        const short* aSrc = aSrc0 + (size_t)(R - r0) * K_DIM;

        for (int kc = 0; kc < K_DIM; kc += KC) {
            __builtin_amdgcn_global_load_lds(
                (const __attribute__((address_space(1))) void*)(aSrc + kc),
                (__attribute__((address_space(3))) void*)(At + ldsOff), 16, 0, 0);
            __builtin_amdgcn_global_load_lds(
                (const __attribute__((address_space(1))) void*)(bSrc0 + kc),
                (__attribute__((address_space(3))) void*)(Bt + ldsOff), 16, 0, 0);
            __syncthreads();

            bf16x8 a[2], b[4];
            #pragma unroll
            for (int mi = 0; mi < 2; ++mi) {
                int i = wi * 32 + mi * 16 + col;
                a[mi] = *(const bf16x8*)(At + i * KC + (((quad + (i >> 1)) & 3) << 3));
            }
            #pragma unroll
            for (int ni = 0; ni < 4; ++ni) {
                int i = wj * 64 + ni * 16 + col;
                b[ni] = *(const bf16x8*)(Bt + i * KC + (((quad + (i >> 1)) & 3) << 3));
            }
            #pragma unroll
            for (int mi = 0; mi < 2; ++mi)
                #pragma unroll
                for (int ni = 0; ni < 4; ++ni)
                    acc[mi][ni] = __builtin_amdgcn_mfma_f32_16x16x32_bf16(a[mi], b[ni], acc[mi][ni], 0, 0, 0);
            __syncthreads();
        }

        // Running min update: v = rn[i] - 2*dot (qn[j] + sqrt deferred;
        // monotone). C/D layout: col = lane&15 (j), row = quad*4 + reg (i).
        float4 rnv4[2];
        #pragma unroll
        for (int mi = 0; mi < 2; ++mi)
            rnv4[mi] = *(const float4*)(rn + R + wi * 32 + mi * 16 + quad * 4);

        #pragma unroll
        for (int ni = 0; ni < 4; ++ni) {
            int jg = j0 + wj * 64 + ni * 16 + col;
            #pragma unroll
            for (int mi = 0; mi < 2; ++mi)
                #pragma unroll
                for (int r = 0; r < 4; ++r) {
                    int ig = R + wi * 32 + mi * 16 + quad * 4 + r;
                    float v = (&rnv4[mi].x)[r] - 2.f * acc[mi][ni][r];
                    bool skip = isReal && (ig == jg);
                    if (!skip && v < minv[ni]) { minv[ni] = v; mini[ni] = ig; }
                }
        }
    }

    // Once per block: cross-quad reduce (lanes +-16/32 share a column), then
    // LDS-merge the two wave-rows, then one global atomic per column.
    #pragma unroll
    for (int ni = 0; ni < 4; ++ni) {
        u64 k = packKey(minv[ni], (unsigned)mini[ni]);
        u64 o = shfl_xor_u64(k, 16); if (o < k) k = o;
        o = shfl_xor_u64(k, 32); if (o < k) k = o;
        if (quad == 0) atomicMin(&red[wj * 64 + ni * 16 + col], k);
    }
    __syncthreads();
    if (tid < BJ) atomicMin(&outKey[j0 + tid], red[tid]);
}

__global__ void finalize_kernel(const u64* __restrict__ realKey, const u64* __restrict__ genKey,
                                const float* __restrict__ rn, const float* __restrict__ gn,
                                float* __restrict__ out, int M) {
    int j = blockIdx.x * blockDim.x + threadIdx.x;
    float a = 0.f;
    if (j < M) {
        u64 gk = genKey[j];
        float mg = unpackVal(gk);
        int idx = (int)(gk & 0xFFFFFFFFu);
        float d1 = sqrtf(fmaxf(mg + gn[j], 0.f));
        u64 rk = realKey[idx];
        float d2 = sqrtf(fmaxf(unpackVal(rk) + rn[idx], 0.f));
        float z = (d2 - d1) * 10.f;   // / TEMP
        a = 1.f / (1.f + expf(-z));
    }
    #pragma unroll
    for (int off = 32; off > 0; off >>= 1) a += __shfl_down(a, off, 64);
    __shared__ float sred[4];
    int lane = threadIdx.x & 63, wv = threadIdx.x >> 6;
    if (lane == 0) sred[wv] = a;
    __syncthreads();
    if (threadIdx.x == 0) {
        float s = sred[0] + sred[1] + sred[2] + sred[3];
        atomicAdd(out, s * (-100.f / (float)M));
    }
}

extern "C" void kernel_launch(void* const* d_in, const int* in_sizes, int n_in,
                              void* d_out, int out_size, void* d_ws, size_t ws_size,
                              hipStream_t stream) {
    const float* real = (const float*)d_in[0];
    const float* gen  = (const float*)d_in[1];
    float* out = (float*)d_out;
    int N = in_sizes[0] / K_DIM;
    int M = in_sizes[1] / K_DIM;

    // Workspace layout (~12.9 MB total):
    u64* realKey = (u64*)d_ws;
    u64* genKey  = realKey + N;
    float* rn = (float*)(genKey + M);
    float* gn = rn + N;
    short* realb = (short*)(gn + M);
    short* genb  = realb + (size_t)N * K_DIM;

    int mx = (N > M ? N : M);
    init_kernel<<<(mx + 255) / 256, 256, 0, stream>>>(realKey, genKey, out, N, M);
    convert_kernel<<<(N + M + 3) / 4, 256, 0, stream>>>(real, gen, realb, genb, rn, gn, N, M);
    dim3 g((mx + BJ - 1) / BJ, SLICES, 2);
    nn_kernel<<<g, 512, 0, stream>>>(realb, genb, rn, realKey, genKey, N, M, SLICES);
    finalize_kernel<<<(M + 255) / 256, 256, 0, stream>>>(realKey, genKey, rn, gn, out, M);
}

// Round 5
// 273.934 us; speedup vs baseline: 7.9053x; 1.0397x over previous
//
#include <hip/hip_runtime.h>
#include <math.h>

#define K_DIM 256
#define BJ 128      // queries per block tile
#define BI 128      // db rows per tile
#define KC 64       // bf16 K-chunk per LDS buffer (2 MFMA k-steps)
#define ITPT 4      // kc-iters per R-tile = K_DIM/KC
#define SLICES 16   // grid (96,16,2)=3072 blocks of 512 thr, 2/CU resident

typedef unsigned long long u64;
typedef __attribute__((ext_vector_type(8))) short bf16x8;   // MFMA A/B frag (4 VGPR)
typedef __attribute__((ext_vector_type(4))) float f32x4;    // MFMA C/D frag

// Monotone map fp32 -> u32 so unsigned compare == float compare.
__device__ __forceinline__ u64 packKey(float v, unsigned idx) {
    unsigned u = __float_as_uint(v);
    u = (u & 0x80000000u) ? ~u : (u | 0x80000000u);
    return ((u64)u << 32) | idx;
}
__device__ __forceinline__ float unpackVal(u64 k) {
    unsigned u = (unsigned)(k >> 32);
    u = (u & 0x80000000u) ? (u ^ 0x80000000u) : ~u;
    return __uint_as_float(u);
}
__device__ __forceinline__ u64 shfl_xor_u64(u64 x, int m) {
    unsigned lo = (unsigned)x, hi = (unsigned)(x >> 32);
    lo = __shfl_xor(lo, m, 64);
    hi = __shfl_xor(hi, m, 64);
    return ((u64)hi << 32) | lo;
}

__device__ __forceinline__ unsigned short f2bf(float x) {   // RNE fp32->bf16
    unsigned u = __float_as_uint(x);
    return (unsigned short)((u + 0x7FFFu + ((u >> 16) & 1u)) >> 16);
}
__device__ __forceinline__ float bf2f(unsigned short b) {
    return __uint_as_float((unsigned)b << 16);
}

__global__ void init_kernel(u64* realKey, u64* genKey, float* out, int N, int M) {
    int t = blockIdx.x * blockDim.x + threadIdx.x;
    if (t < N) realKey[t] = ~0ull;
    if (t < M) genKey[t] = ~0ull;
    if (t == 0) out[0] = 0.f;
}

// One wave per row: quantize fp32->bf16 AND compute the norm of the QUANTIZED
// vector (keeps rn/gn exactly consistent with the bf16 MFMA dot products).
__global__ void convert_kernel(const float* __restrict__ real, const float* __restrict__ gen,
                               short* __restrict__ realb, short* __restrict__ genb,
                               float* __restrict__ rn, float* __restrict__ gn, int N, int M) {
    int wv = (blockIdx.x * blockDim.x + threadIdx.x) >> 6;
    int lane = threadIdx.x & 63;
    if (wv >= N + M) return;
    const float* src;
    short* dst;
    if (wv < N) { src = real + (size_t)wv * K_DIM; dst = realb + (size_t)wv * K_DIM; }
    else        { src = gen + (size_t)(wv - N) * K_DIM; dst = genb + (size_t)(wv - N) * K_DIM; }
    float4 v = ((const float4*)src)[lane];
    ushort4 b;
    b.x = f2bf(v.x); b.y = f2bf(v.y); b.z = f2bf(v.z); b.w = f2bf(v.w);
    float qx = bf2f(b.x), qy = bf2f(b.y), qz = bf2f(b.z), qw = bf2f(b.w);
    float s = qx * qx + qy * qy + qz * qz + qw * qw;
    ((ushort4*)dst)[lane] = b;
    #pragma unroll
    for (int off = 32; off > 0; off >>= 1) s += __shfl_down(s, off, 64);
    if (lane == 0) { if (wv < N) rn[wv] = s; else gn[wv - N] = s; }
}

// Fused bf16-MFMA GEMM + column-min(+argmin). blockIdx.z: 0 = real queries
// (diagonal excluded), 1 = gen queries. Min is over db rows (real).
//
// Pipelined K-loop (ONE barrier per kc-iter, prefetch distance 1):
//   iter k: [__syncthreads]  - drains OWN prefetch issued at k-1 (vmcnt had a
//                              full iter to land) and certifies all waves
//                              finished reading buf (k+1)&1 at iter k-1
//           [prefetch k+1 into buf (k+1)&1]   - safe per the barrier
//           [ds_read frags from buf k&1, 16 MFMA/wave]
// LDS rows are 128B (8x16B chunks); chunk placement rotate-swizzled
// phys=(logical+row)&7 so each quad's 16 frag reads tile all 32 banks
// exactly twice (2-way = free). Running min kept in registers across
// R-tiles; pack/shfl/atomic reduction once per block.
__global__ __launch_bounds__(512, 4) void nn_kernel(
    const short* __restrict__ realb, const short* __restrict__ genb,
    const float* __restrict__ rn,
    u64* __restrict__ realKey, u64* __restrict__ genKey,
    int N, int M, int slices) {

    const bool isReal = (blockIdx.z == 0);
    const short* __restrict__ q = isReal ? realb : genb;
    u64* outKey = isReal ? realKey : genKey;

    const int j0 = blockIdx.x * BJ;
    const int rowsPerSlice = N / slices;        // 768
    const int r0 = blockIdx.y * rowsPerSlice;
    const int tiles = rowsPerSlice / BI;        // 6
    const int iters = tiles * ITPT;             // 24

    __shared__ short At[2][BI * KC];   // 2 x 16 KB
    __shared__ short Bt[2][BJ * KC];   // 2 x 16 KB
    __shared__ u64 red[BJ];

    const int tid = threadIdx.x;
    const int lane = tid & 63;
    const int w = tid >> 6;         // 0..7
    const int wi = w >> 1;          // wave's 32-row block (i): 0..3
    const int wj = w & 1;           // wave's 64-col block (j): 0..1
    const int quad = lane >> 4;
    const int col = lane & 15;

    // Staging: 2 rounds x (64 rows x 8 phys chunks). Thread -> row, phys
    // chunk; fetch logical chunk (phys - row) & 7 from global.
    const int srow0 = tid >> 3;
    const int sphys = tid & 7;
    int soff[2];
    #pragma unroll
    for (int rd = 0; rd < 2; ++rd) {
        int row = srow0 + rd * 64;
        int lc = (sphys - row) & 7;
        soff[rd] = row * K_DIM + lc * 8;
    }
    const int ldsW = (tid & ~63) << 3;   // wave-uniform dest offset (shorts)

    const short* aTileBase = realb + (size_t)r0 * K_DIM;
    const short* bTileBase = q + (size_t)j0 * K_DIM;

    if (tid < BJ) red[tid] = ~0ull;

    float minv[4];
    int mini[4];
    #pragma unroll
    for (int ni = 0; ni < 4; ++ni) { minv[ni] = 3.4e38f; mini[ni] = 0; }

    f32x4 acc[2][4];
    #pragma unroll
    for (int mi = 0; mi < 2; ++mi)
        #pragma unroll
        for (int ni = 0; ni < 4; ++ni)
            acc[mi][ni] = (f32x4){0.f, 0.f, 0.f, 0.f};

    auto prefetch = [&](int it) {
        int buf = it & 1;
        const short* aB = aTileBase + (size_t)(it >> 2) * BI * K_DIM + (it & 3) * KC;
        const short* bB = bTileBase + (it & 3) * KC;
        #pragma unroll
        for (int rd = 0; rd < 2; ++rd) {
            __builtin_amdgcn_global_load_lds(
                (const __attribute__((address_space(1))) void*)(aB + soff[rd]),
                (__attribute__((address_space(3))) void*)(&At[buf][rd * 4096 + ldsW]), 16, 0, 0);
            __builtin_amdgcn_global_load_lds(
                (const __attribute__((address_space(1))) void*)(bB + soff[rd]),
                (__attribute__((address_space(3))) void*)(&Bt[buf][rd * 4096 + ldsW]), 16, 0, 0);
        }
    };

    prefetch(0);

    for (int it = 0; it < iters; ++it) {
        __syncthreads();
        if (it + 1 < iters) prefetch(it + 1);

        const short* Ab = At[it & 1];
        const short* Bb = Bt[it & 1];
        #pragma unroll
        for (int ks = 0; ks < 2; ++ks) {
            bf16x8 a[2], b[4];
            #pragma unroll
            for (int mi = 0; mi < 2; ++mi) {
                int i = wi * 32 + mi * 16 + col;
                int c = (4 * ks + quad + i) & 7;
                a[mi] = *(const bf16x8*)(Ab + i * KC + c * 8);
            }
            #pragma unroll
            for (int ni = 0; ni < 4; ++ni) {
                int i = wj * 64 + ni * 16 + col;
                int c = (4 * ks + quad + i) & 7;
                b[ni] = *(const bf16x8*)(Bb + i * KC + c * 8);
            }
            #pragma unroll
            for (int mi = 0; mi < 2; ++mi)
                #pragma unroll
                for (int ni = 0; ni < 4; ++ni)
                    acc[mi][ni] = __builtin_amdgcn_mfma_f32_16x16x32_bf16(a[mi], b[ni], acc[mi][ni], 0, 0, 0);
        }

        if ((it & 3) == 3) {
            // End of R-tile: running min update. v = rn[i] - 2*dot
            // (qn[j] + sqrt deferred; monotone). C/D: col=lane&15 (j),
            // row = quad*4 + reg (i).
            int R = r0 + (it >> 2) * BI;
            float4 rnv4[2];
            #pragma unroll
            for (int mi = 0; mi < 2; ++mi)
                rnv4[mi] = *(const float4*)(rn + R + wi * 32 + mi * 16 + quad * 4);

            #pragma unroll
            for (int ni = 0; ni < 4; ++ni) {
                int jg = j0 + wj * 64 + ni * 16 + col;
                #pragma unroll
                for (int mi = 0; mi < 2; ++mi)
                    #pragma unroll
                    for (int r = 0; r < 4; ++r) {
                        int ig = R + wi * 32 + mi * 16 + quad * 4 + r;
                        float v = (&rnv4[mi].x)[r] - 2.f * acc[mi][ni][r];
                        bool skip = isReal && (ig == jg);
                        if (!skip && v < minv[ni]) { minv[ni] = v; mini[ni] = ig; }
                    }
            }
            #pragma unroll
            for (int mi = 0; mi < 2; ++mi)
                #pragma unroll
                for (int ni = 0; ni < 4; ++ni)
                    acc[mi][ni] = (f32x4){0.f, 0.f, 0.f, 0.f};
        }
    }

    // Once per block: cross-quad reduce (lanes +-16/32 share a column), then
    // LDS-merge, then one global atomic per column.
    #pragma unroll
    for (int ni = 0; ni < 4; ++ni) {
        u64 k = packKey(minv[ni], (unsigned)mini[ni]);
        u64 o = shfl_xor_u64(k, 16); if (o < k) k = o;
        o = shfl_xor_u64(k, 32); if (o < k) k = o;
        if (quad == 0) atomicMin(&red[wj * 64 + ni * 16 + col], k);
    }
    __syncthreads();
    if (tid < BJ) atomicMin(&outKey[j0 + tid], red[tid]);
}

__global__ void finalize_kernel(const u64* __restrict__ realKey, const u64* __restrict__ genKey,
                                const float* __restrict__ rn, const float* __restrict__ gn,
                                float* __restrict__ out, int M) {
    int j = blockIdx.x * blockDim.x + threadIdx.x;
    float a = 0.f;
    if (j < M) {
        u64 gk = genKey[j];
        float mg = unpackVal(gk);
        int idx = (int)(gk & 0xFFFFFFFFu);
        float d1 = sqrtf(fmaxf(mg + gn[j], 0.f));
        u64 rk = realKey[idx];
        float d2 = sqrtf(fmaxf(unpackVal(rk) + rn[idx], 0.f));
        float z = (d2 - d1) * 10.f;   // / TEMP
        a = 1.f / (1.f + expf(-z));
    }
    #pragma unroll
    for (int off = 32; off > 0; off >>= 1) a += __shfl_down(a, off, 64);
    __shared__ float sred[4];
    int lane = threadIdx.x & 63, wv = threadIdx.x >> 6;
    if (lane == 0) sred[wv] = a;
    __syncthreads();
    if (threadIdx.x == 0) {
        float s = sred[0] + sred[1] + sred[2] + sred[3];
        atomicAdd(out, s * (-100.f / (float)M));
    }
}

extern "C" void kernel_launch(void* const* d_in, const int* in_sizes, int n_in,
                              void* d_out, int out_size, void* d_ws, size_t ws_size,
                              hipStream_t stream) {
    const float* real = (const float*)d_in[0];
    const float* gen  = (const float*)d_in[1];
    float* out = (float*)d_out;
    int N = in_sizes[0] / K_DIM;
    int M = in_sizes[1] / K_DIM;

    // Workspace layout (~12.9 MB total):
    u64* realKey = (u64*)d_ws;
    u64* genKey  = realKey + N;
    float* rn = (float*)(genKey + M);
    float* gn = rn + N;
    short* realb = (short*)(gn + M);
    short* genb  = realb + (size_t)N * K_DIM;

    int mx = (N > M ? N : M);
    init_kernel<<<(mx + 255) / 256, 256, 0, stream>>>(realKey, genKey, out, N, M);
    convert_kernel<<<(N + M + 3) / 4, 256, 0, stream>>>(real, gen, realb, genb, rn, gn, N, M);
    dim3 g((mx + BJ - 1) / BJ, SLICES, 2);
    nn_kernel<<<g, 512, 0, stream>>>(realb, genb, rn, realKey, genKey, N, M, SLICES);
    finalize_kernel<<<(M + 255) / 256, 256, 0, stream>>>(realKey, genKey, rn, gn, out, M);
}

// Round 6
// 259.115 us; speedup vs baseline: 8.3574x; 1.0572x over previous
//
#include <hip/hip_runtime.h>
#include <math.h>

#define K_DIM 256
#define BJ 128      // queries per block tile
#define BI 128      // db rows per tile
#define KC 32       // bf16 K-chunk per LDS buffer (1 MFMA k-step)
#define SLICES 16   // grid (96,16,2)=3072 blocks of 256 thr, 4/CU resident

typedef unsigned long long u64;
typedef __attribute__((ext_vector_type(8))) short bf16x8;   // MFMA A/B frag (4 VGPR)
typedef __attribute__((ext_vector_type(4))) float f32x4;    // MFMA C/D frag

// Monotone map fp32 -> u32 so unsigned compare == float compare.
__device__ __forceinline__ u64 packKey(float v, unsigned idx) {
    unsigned u = __float_as_uint(v);
    u = (u & 0x80000000u) ? ~u : (u | 0x80000000u);
    return ((u64)u << 32) | idx;
}
__device__ __forceinline__ float unpackVal(u64 k) {
    unsigned u = (unsigned)(k >> 32);
    u = (u & 0x80000000u) ? (u ^ 0x80000000u) : ~u;
    return __uint_as_float(u);
}
__device__ __forceinline__ u64 shfl_xor_u64(u64 x, int m) {
    unsigned lo = (unsigned)x, hi = (unsigned)(x >> 32);
    lo = __shfl_xor(lo, m, 64);
    hi = __shfl_xor(hi, m, 64);
    return ((u64)hi << 32) | lo;
}

__device__ __forceinline__ unsigned short f2bf(float x) {   // RNE fp32->bf16
    unsigned u = __float_as_uint(x);
    return (unsigned short)((u + 0x7FFFu + ((u >> 16) & 1u)) >> 16);
}
__device__ __forceinline__ float bf2f(unsigned short b) {
    return __uint_as_float((unsigned)b << 16);
}

// One wave per row: quantize fp32->bf16, compute the norm of the QUANTIZED
// vector (keeps rn/gn consistent with the bf16 MFMA dots), and init the
// min-key arrays + output accumulator (fused former init_kernel).
__global__ void convert_kernel(const float* __restrict__ real, const float* __restrict__ gen,
                               short* __restrict__ realb, short* __restrict__ genb,
                               float* __restrict__ rn, float* __restrict__ gn,
                               u64* __restrict__ realKey, u64* __restrict__ genKey,
                               float* __restrict__ out, int N, int M) {
    int wv = (blockIdx.x * blockDim.x + threadIdx.x) >> 6;
    int lane = threadIdx.x & 63;
    if (wv >= N + M) return;
    const float* src;
    short* dst;
    if (wv < N) { src = real + (size_t)wv * K_DIM; dst = realb + (size_t)wv * K_DIM; }
    else        { src = gen + (size_t)(wv - N) * K_DIM; dst = genb + (size_t)(wv - N) * K_DIM; }
    float4 v = ((const float4*)src)[lane];
    ushort4 b;
    b.x = f2bf(v.x); b.y = f2bf(v.y); b.z = f2bf(v.z); b.w = f2bf(v.w);
    float qx = bf2f(b.x), qy = bf2f(b.y), qz = bf2f(b.z), qw = bf2f(b.w);
    float s = qx * qx + qy * qy + qz * qz + qw * qw;
    ((ushort4*)dst)[lane] = b;
    #pragma unroll
    for (int off = 32; off > 0; off >>= 1) s += __shfl_down(s, off, 64);
    if (lane == 0) {
        if (wv < N) { rn[wv] = s; realKey[wv] = ~0ull; }
        else        { gn[wv - N] = s; genKey[wv - N] = ~0ull; }
        if (wv == 0) out[0] = 0.f;
    }
}

// Fused bf16-MFMA GEMM + column-min(+argmin). blockIdx.z: 0 = real queries
// (diagonal excluded), 1 = gen queries. Min is over db rows (real).
//
// 256 threads = 4 waves in 2x2; each wave owns a 64x64 sub-tile (4x4 frags
// of 16x16x32, 64 acc regs) -> LDS B/FLOP = 0.031 (was 0.047 at 32x64);
// KC=32 double-buffered = 33 KiB LDS -> 4 blocks/CU (4 desynced barrier
// domains). Pipelined K-loop, ONE barrier per iter, prefetch distance 1:
//   iter k: [__syncthreads] -> [prefetch k+1 into buf^1] -> [frags+16 MFMA]
// LDS 16B-chunk placement rotate-swizzled phys=(quad+(row>>1))&3 (verified
// 0-conflict in R3). All frag LDS offsets precomputed loop-invariant.
// Running min in registers; pack/shfl/atomic reduction once per block.
__global__ __launch_bounds__(256, 4) void nn_kernel(
    const short* __restrict__ realb, const short* __restrict__ genb,
    const float* __restrict__ rn,
    u64* __restrict__ realKey, u64* __restrict__ genKey,
    int N, int M, int slices) {

    const bool isReal = (blockIdx.z == 0);
    const short* __restrict__ q = isReal ? realb : genb;
    u64* outKey = isReal ? realKey : genKey;

    const int j0 = blockIdx.x * BJ;
    const int rowsPerSlice = N / slices;        // 768
    const int r0 = blockIdx.y * rowsPerSlice;
    const int tiles = rowsPerSlice / BI;        // 6
    const int iters = tiles * (K_DIM / KC);     // 48

    __shared__ short At[2][BI * KC];   // 2 x 8 KB
    __shared__ short Bt[2][BJ * KC];   // 2 x 8 KB
    __shared__ u64 red[BJ];            // 1 KB

    const int tid = threadIdx.x;
    const int lane = tid & 63;
    const int w = tid >> 6;         // 0..3
    const int wi = w >> 1;          // wave's 64-row block (i): 0..1
    const int wj = w & 1;           // wave's 64-col block (j): 0..1
    const int quad = lane >> 4;
    const int col = lane & 15;

    // Staging: 2 rounds x (64 rows x 4 phys 16B chunks); 2 A + 2 B issues
    // per thread per iter. Fetch logical chunk (phys - (row>>1)) & 3.
    const int srow = tid >> 2;            // 0..63
    const int schunk = tid & 3;
    int soff[2];
    #pragma unroll
    for (int rd = 0; rd < 2; ++rd) {
        int row = srow + rd * 64;
        int lc = (schunk - (row >> 1)) & 3;
        soff[rd] = row * K_DIM + lc * 8;
    }
    const int ldsW = (tid & ~63) << 3;   // wave-uniform dest offset (shorts)

    // Loop-invariant fragment read offsets (shorts).
    int aOffs[4], bOffs[4];
    #pragma unroll
    for (int mi = 0; mi < 4; ++mi) {
        int i = wi * 64 + mi * 16 + col;
        aOffs[mi] = i * KC + (((quad + (i >> 1)) & 3) << 3);
    }
    #pragma unroll
    for (int ni = 0; ni < 4; ++ni) {
        int i = wj * 64 + ni * 16 + col;
        bOffs[ni] = i * KC + (((quad + (i >> 1)) & 3) << 3);
    }

    const short* aTileBase = realb + (size_t)r0 * K_DIM;
    const short* bTileBase = q + (size_t)j0 * K_DIM;

    if (tid < BJ) red[tid] = ~0ull;

    float minv[4];
    int mini[4];
    #pragma unroll
    for (int ni = 0; ni < 4; ++ni) { minv[ni] = 3.4e38f; mini[ni] = 0; }

    f32x4 acc[4][4];
    #pragma unroll
    for (int mi = 0; mi < 4; ++mi)
        #pragma unroll
        for (int ni = 0; ni < 4; ++ni)
            acc[mi][ni] = (f32x4){0.f, 0.f, 0.f, 0.f};

    auto prefetch = [&](int it) {
        int buf = it & 1;
        const short* aB = aTileBase + (size_t)(it >> 3) * BI * K_DIM + (it & 7) * KC;
        const short* bB = bTileBase + (it & 7) * KC;
        #pragma unroll
        for (int rd = 0; rd < 2; ++rd) {
            __builtin_amdgcn_global_load_lds(
                (const __attribute__((address_space(1))) void*)(aB + soff[rd]),
                (__attribute__((address_space(3))) void*)(&At[buf][rd * 2048 + ldsW]), 16, 0, 0);
            __builtin_amdgcn_global_load_lds(
                (const __attribute__((address_space(1))) void*)(bB + soff[rd]),
                (__attribute__((address_space(3))) void*)(&Bt[buf][rd * 2048 + ldsW]), 16, 0, 0);
        }
    };

    prefetch(0);

    for (int it = 0; it < iters; ++it) {
        __syncthreads();
        if (it + 1 < iters) prefetch(it + 1);

        const short* Ab = At[it & 1];
        const short* Bb = Bt[it & 1];
        bf16x8 a[4], b[4];
        #pragma unroll
        for (int mi = 0; mi < 4; ++mi) a[mi] = *(const bf16x8*)(Ab + aOffs[mi]);
        #pragma unroll
        for (int ni = 0; ni < 4; ++ni) b[ni] = *(const bf16x8*)(Bb + bOffs[ni]);
        #pragma unroll
        for (int mi = 0; mi < 4; ++mi)
            #pragma unroll
            for (int ni = 0; ni < 4; ++ni)
                acc[mi][ni] = __builtin_amdgcn_mfma_f32_16x16x32_bf16(a[mi], b[ni], acc[mi][ni], 0, 0, 0);

        if ((it & 7) == 7) {
            // End of R-tile: running min update. v = rn[i] - 2*dot
            // (qn[j] + sqrt deferred; monotone). C/D: col=lane&15 (j),
            // row = quad*4 + reg (i).
            int R = r0 + (it >> 3) * BI;
            float4 rnv4[4];
            #pragma unroll
            for (int mi = 0; mi < 4; ++mi)
                rnv4[mi] = *(const float4*)(rn + R + wi * 64 + mi * 16 + quad * 4);

            #pragma unroll
            for (int ni = 0; ni < 4; ++ni) {
                int jg = j0 + wj * 64 + ni * 16 + col;
                #pragma unroll
                for (int mi = 0; mi < 4; ++mi)
                    #pragma unroll
                    for (int r = 0; r < 4; ++r) {
                        int ig = R + wi * 64 + mi * 16 + quad * 4 + r;
                        float v = (&rnv4[mi].x)[r] - 2.f * acc[mi][ni][r];
                        bool skip = isReal && (ig == jg);
                        if (!skip && v < minv[ni]) { minv[ni] = v; mini[ni] = ig; }
                    }
            }
            #pragma unroll
            for (int mi = 0; mi < 4; ++mi)
                #pragma unroll
                for (int ni = 0; ni < 4; ++ni)
                    acc[mi][ni] = (f32x4){0.f, 0.f, 0.f, 0.f};
        }
    }

    // Once per block: cross-quad reduce (lanes +-16/32 share a column), then
    // LDS-merge the two wave-rows (wi=0,1), then one global atomic per col.
    #pragma unroll
    for (int ni = 0; ni < 4; ++ni) {
        u64 k = packKey(minv[ni], (unsigned)mini[ni]);
        u64 o = shfl_xor_u64(k, 16); if (o < k) k = o;
        o = shfl_xor_u64(k, 32); if (o < k) k = o;
        if (quad == 0) atomicMin(&red[wj * 64 + ni * 16 + col], k);
    }
    __syncthreads();
    if (tid < BJ) atomicMin(&outKey[j0 + tid], red[tid]);
}

__global__ void finalize_kernel(const u64* __restrict__ realKey, const u64* __restrict__ genKey,
                                const float* __restrict__ rn, const float* __restrict__ gn,
                                float* __restrict__ out, int M) {
    int j = blockIdx.x * blockDim.x + threadIdx.x;
    float a = 0.f;
    if (j < M) {
        u64 gk = genKey[j];
        float mg = unpackVal(gk);
        int idx = (int)(gk & 0xFFFFFFFFu);
        float d1 = sqrtf(fmaxf(mg + gn[j], 0.f));
        u64 rk = realKey[idx];
        float d2 = sqrtf(fmaxf(unpackVal(rk) + rn[idx], 0.f));
        float z = (d2 - d1) * 10.f;   // / TEMP
        a = 1.f / (1.f + expf(-z));
    }
    #pragma unroll
    for (int off = 32; off > 0; off >>= 1) a += __shfl_down(a, off, 64);
    __shared__ float sred[4];
    int lane = threadIdx.x & 63, wv = threadIdx.x >> 6;
    if (lane == 0) sred[wv] = a;
    __syncthreads();
    if (threadIdx.x == 0) {
        float s = sred[0] + sred[1] + sred[2] + sred[3];
        atomicAdd(out, s * (-100.f / (float)M));
    }
}

extern "C" void kernel_launch(void* const* d_in, const int* in_sizes, int n_in,
                              void* d_out, int out_size, void* d_ws, size_t ws_size,
                              hipStream_t stream) {
    const float* real = (const float*)d_in[0];
    const float* gen  = (const float*)d_in[1];
    float* out = (float*)d_out;
    int N = in_sizes[0] / K_DIM;
    int M = in_sizes[1] / K_DIM;

    // Workspace layout (~12.9 MB total):
    u64* realKey = (u64*)d_ws;
    u64* genKey  = realKey + N;
    float* rn = (float*)(genKey + M);
    float* gn = rn + N;
    short* realb = (short*)(gn + M);
    short* genb  = realb + (size_t)N * K_DIM;

    int mx = (N > M ? N : M);
    convert_kernel<<<(N + M + 3) / 4, 256, 0, stream>>>(real, gen, realb, genb, rn, gn,
                                                        realKey, genKey, out, N, M);
    dim3 g((mx + BJ - 1) / BJ, SLICES, 2);
    nn_kernel<<<g, 256, 0, stream>>>(realb, genb, rn, realKey, genKey, N, M, SLICES);
    finalize_kernel<<<(M + 255) / 256, 256, 0, stream>>>(realKey, genKey, rn, gn, out, M);
}

// Round 7
// 246.982 us; speedup vs baseline: 8.7680x; 1.0491x over previous
//
#include <hip/hip_runtime.h>
#include <math.h>

#define K_DIM 256
#define BJ 128      // queries per block tile
#define BI 128      // db rows per tile
#define SLICES 16   // grid (96,16,2)=3072 blocks of 256 thr

typedef unsigned long long u64;
typedef __attribute__((ext_vector_type(8))) short bf16x8;   // MFMA A/B frag (4 VGPR)
typedef __attribute__((ext_vector_type(4))) float f32x4;    // MFMA C/D frag

// Monotone map fp32 -> u32 so unsigned compare == float compare.
__device__ __forceinline__ u64 packKey(float v, unsigned idx) {
    unsigned u = __float_as_uint(v);
    u = (u & 0x80000000u) ? ~u : (u | 0x80000000u);
    return ((u64)u << 32) | idx;
}
__device__ __forceinline__ float unpackVal(u64 k) {
    unsigned u = (unsigned)(k >> 32);
    u = (u & 0x80000000u) ? (u ^ 0x80000000u) : ~u;
    return __uint_as_float(u);
}
__device__ __forceinline__ u64 shfl_xor_u64(u64 x, int m) {
    unsigned lo = (unsigned)x, hi = (unsigned)(x >> 32);
    lo = __shfl_xor(lo, m, 64);
    hi = __shfl_xor(hi, m, 64);
    return ((u64)hi << 32) | lo;
}

__device__ __forceinline__ unsigned short f2bf(float x) {   // RNE fp32->bf16
    unsigned u = __float_as_uint(x);
    return (unsigned short)((u + 0x7FFFu + ((u >> 16) & 1u)) >> 16);
}
__device__ __forceinline__ float bf2f(unsigned short b) {
    return __uint_as_float((unsigned)b << 16);
}

// Packed fragment layout (per tensor): PK[c][i16][lane][j] shorts, where
// c = k-chunk (k = 32c + 8*(lane>>4) + j), i16 = row/16, row = 16*i16 +
// (lane&15), j in [0,8). One (c,i16) cell = 64 lanes x 16 B = 1 KB = one
// MFMA operand fragment, loadable as a single coalesced dwordx4 per lane.
// (16x16x32 A and B operand layouts are identical, so one packing serves
// both sides.)

// One wave per row: quantize fp32->bf16 into PACKED layout, compute the
// norm of the QUANTIZED vector, init min-key arrays + output.
__global__ void convert_kernel(const float* __restrict__ real, const float* __restrict__ gen,
                               short* __restrict__ realP, short* __restrict__ genP,
                               float* __restrict__ rn, float* __restrict__ gn,
                               u64* __restrict__ realKey, u64* __restrict__ genKey,
                               float* __restrict__ out, int N, int M) {
    int wv = (blockIdx.x * blockDim.x + threadIdx.x) >> 6;
    int lane = threadIdx.x & 63;
    if (wv >= N + M) return;
    const float* src;
    short* dstP;
    int r, NT;
    if (wv < N) { src = real + (size_t)wv * K_DIM; dstP = realP; r = wv; NT = N >> 4; }
    else        { src = gen + (size_t)(wv - N) * K_DIM; dstP = genP; r = wv - N; NT = M >> 4; }
    float4 v = ((const float4*)src)[lane];   // k = 4*lane .. 4*lane+3
    ushort4 b;
    b.x = f2bf(v.x); b.y = f2bf(v.y); b.z = f2bf(v.z); b.w = f2bf(v.w);
    float qx = bf2f(b.x), qy = bf2f(b.y), qz = bf2f(b.z), qw = bf2f(b.w);
    float s = qx * qx + qy * qy + qz * qz + qw * qw;
    // dest: c = lane>>3, quad = (lane>>1)&3, byte group j0 = (lane&1)*4
    int c = lane >> 3;
    int lane_p = (r & 15) + (((lane >> 1) & 3) << 4);
    size_t sidx = (((size_t)c * NT + (r >> 4)) * 64 + lane_p) * 8 + (lane & 1) * 4;
    *(ushort4*)(dstP + sidx) = b;
    #pragma unroll
    for (int off = 32; off > 0; off >>= 1) s += __shfl_down(s, off, 64);
    if (lane == 0) {
        if (wv < N) { rn[wv] = s; realKey[wv] = ~0ull; }
        else        { gn[wv - N] = s; genKey[wv - N] = ~0ull; }
        if (wv == 0) out[0] = 0.f;
    }
}

// Fused bf16-MFMA GEMM + column-min(+argmin). blockIdx.z: 0 = real queries
// (diagonal excluded), 1 = gen queries. Min is over db rows (real).
//
// BARRIER-FREE K-loop: operands are pre-packed in fragment order, so each
// wave loads its 4 A-frags + 4 B-frags with coalesced global_load_dwordx4
// (imm offsets 0/1024/2048/3072 off one per-wave address) straight into
// VGPRs — no LDS staging, no __syncthreads in the hot loop. Register
// ping-pong (a0/b0 vs a1/b1) gives prefetch distance 1; the compiler emits
// per-wave partial vmcnt waits (no barrier-amplified vmcnt(0) drain — the
// structural fix for the ~36% plateau of the staged K-loop). L1 dedupes
// the 2x intra-block sharing of each fragment (wi/wj pairs).
__global__ __launch_bounds__(256, 3) void nn_kernel(
    const short* __restrict__ realP, const short* __restrict__ genP,
    const float* __restrict__ rn,
    u64* __restrict__ realKey, u64* __restrict__ genKey,
    int N, int M) {

    const bool isReal = (blockIdx.z == 0);
    const short* __restrict__ qP = isReal ? realP : genP;
    u64* outKey = isReal ? realKey : genKey;

    const int j0 = blockIdx.x * BJ;
    const int rowsPerSlice = N / SLICES;              // 768
    const int r0 = blockIdx.y * rowsPerSlice;
    const int iters = (rowsPerSlice / BI) * (K_DIM / 32);   // 48

    __shared__ u64 red[BJ];

    const int tid = threadIdx.x;
    const int lane = tid & 63;
    const int w = tid >> 6;         // 0..3
    const int wi = w >> 1;          // wave's 64-row block (i): 0..1
    const int wj = w & 1;           // wave's 64-col block (j): 0..1
    const int quad = lane >> 4;
    const int col = lane & 15;

    const size_t CSTEPA = (size_t)(N >> 4) * 1024;    // bytes per c+1 (A)
    const size_t CSTEPB = (size_t)((isReal ? N : M) >> 4) * 1024;

    // Per-wave fragment addresses (byte pointers), frag mi/ni at +mi*1024.
    const char* aP = (const char*)realP + (((size_t)((r0 >> 4) + wi * 4) * 64 + lane) * 16);
    const char* bP = (const char*)qP   + (((size_t)((j0 >> 4) + wj * 4) * 64 + lane) * 16);

    if (tid < BJ) red[tid] = ~0ull;

    float minv[4];
    int mini[4];
    #pragma unroll
    for (int ni = 0; ni < 4; ++ni) { minv[ni] = 3.4e38f; mini[ni] = 0; }

    f32x4 acc[4][4];
    #pragma unroll
    for (int mi = 0; mi < 4; ++mi)
        #pragma unroll
        for (int ni = 0; ni < 4; ++ni)
            acc[mi][ni] = (f32x4){0.f, 0.f, 0.f, 0.f};

    auto loadFrags = [&](bf16x8* a, bf16x8* b) {
        #pragma unroll
        for (int x = 0; x < 4; ++x) {
            a[x] = *(const bf16x8*)(aP + x * 1024);
            b[x] = *(const bf16x8*)(bP + x * 1024);
        }
    };
    // Advance pointers past iter `it` (A: row-tile steps every 8 chunks;
    // B: fixed row-tile, k-chunk cycles 0..7).
    auto advance = [&](int it) {
        if ((it & 7) == 7) {
            aP += 8192 - 7 * (ptrdiff_t)CSTEPA;
            bP -= 7 * (ptrdiff_t)CSTEPB;
        } else {
            aP += CSTEPA;
            bP += CSTEPB;
        }
    };
    auto mfmaAll = [&](const bf16x8* a, const bf16x8* b) {
        #pragma unroll
        for (int mi = 0; mi < 4; ++mi)
            #pragma unroll
            for (int ni = 0; ni < 4; ++ni)
                acc[mi][ni] = __builtin_amdgcn_mfma_f32_16x16x32_bf16(a[mi], b[ni], acc[mi][ni], 0, 0, 0);
    };
    auto epilogue = [&](int R) {
        // v = rn[i] - 2*dot (qn[j] + sqrt deferred; monotone).
        // C/D layout: col = lane&15 (j), row = quad*4 + reg (i).
        float4 rnv4[4];
        #pragma unroll
        for (int mi = 0; mi < 4; ++mi)
            rnv4[mi] = *(const float4*)(rn + R + wi * 64 + mi * 16 + quad * 4);
        #pragma unroll
        for (int ni = 0; ni < 4; ++ni) {
            int jg = j0 + wj * 64 + ni * 16 + col;
            #pragma unroll
            for (int mi = 0; mi < 4; ++mi)
                #pragma unroll
                for (int r = 0; r < 4; ++r) {
                    int ig = R + wi * 64 + mi * 16 + quad * 4 + r;
                    float v = (&rnv4[mi].x)[r] - 2.f * acc[mi][ni][r];
                    bool skip = isReal && (ig == jg);
                    if (!skip && v < minv[ni]) { minv[ni] = v; mini[ni] = ig; }
                }
        }
        #pragma unroll
        for (int mi = 0; mi < 4; ++mi)
            #pragma unroll
            for (int ni = 0; ni < 4; ++ni)
                acc[mi][ni] = (f32x4){0.f, 0.f, 0.f, 0.f};
    };

    bf16x8 a0[4], b0[4], a1[4], b1[4];
    loadFrags(a0, b0);
    advance(0);

    for (int it = 0; it < iters; it += 2) {
        loadFrags(a1, b1);              // prefetch it+1
        advance(it + 1);
        mfmaAll(a0, b0);                // compute it (even: never a tile end)
        if (it + 2 < iters) {
            loadFrags(a0, b0);          // prefetch it+2
            advance(it + 2);
        }
        mfmaAll(a1, b1);                // compute it+1
        if (((it + 1) & 7) == 7)        // tile boundary (it+1 = 7 mod 8)
            epilogue(r0 + ((it + 1) >> 3) * BI);
    }

    // Block reduction: cross-quad shuffle (lanes +-16/32 share a column),
    // LDS merge of the two wi wave-rows, one global atomic per column.
    __syncthreads();   // red[] init visible
    #pragma unroll
    for (int ni = 0; ni < 4; ++ni) {
        u64 k = packKey(minv[ni], (unsigned)mini[ni]);
        u64 o = shfl_xor_u64(k, 16); if (o < k) k = o;
        o = shfl_xor_u64(k, 32); if (o < k) k = o;
        if (quad == 0) atomicMin(&red[wj * 64 + ni * 16 + col], k);
    }
    __syncthreads();
    if (tid < BJ) atomicMin(&outKey[j0 + tid], red[tid]);
}

__global__ void finalize_kernel(const u64* __restrict__ realKey, const u64* __restrict__ genKey,
                                const float* __restrict__ rn, const float* __restrict__ gn,
                                float* __restrict__ out, int M) {
    int j = blockIdx.x * blockDim.x + threadIdx.x;
    float a = 0.f;
    if (j < M) {
        u64 gk = genKey[j];
        float mg = unpackVal(gk);
        int idx = (int)(gk & 0xFFFFFFFFu);
        float d1 = sqrtf(fmaxf(mg + gn[j], 0.f));
        u64 rk = realKey[idx];
        float d2 = sqrtf(fmaxf(unpackVal(rk) + rn[idx], 0.f));
        float z = (d2 - d1) * 10.f;   // / TEMP
        a = 1.f / (1.f + expf(-z));
    }
    #pragma unroll
    for (int off = 32; off > 0; off >>= 1) a += __shfl_down(a, off, 64);
    __shared__ float sred[4];
    int lane = threadIdx.x & 63, wv = threadIdx.x >> 6;
    if (lane == 0) sred[wv] = a;
    __syncthreads();
    if (threadIdx.x == 0) {
        float s = sred[0] + sred[1] + sred[2] + sred[3];
        atomicAdd(out, s * (-100.f / (float)M));
    }
}

extern "C" void kernel_launch(void* const* d_in, const int* in_sizes, int n_in,
                              void* d_out, int out_size, void* d_ws, size_t ws_size,
                              hipStream_t stream) {
    const float* real = (const float*)d_in[0];
    const float* gen  = (const float*)d_in[1];
    float* out = (float*)d_out;
    int N = in_sizes[0] / K_DIM;
    int M = in_sizes[1] / K_DIM;

    // Workspace layout (~12.9 MB total):
    u64* realKey = (u64*)d_ws;
    u64* genKey  = realKey + N;
    float* rn = (float*)(genKey + M);
    float* gn = rn + N;
    short* realP = (short*)(gn + M);
    short* genP  = realP + (size_t)N * K_DIM;

    int mx = (N > M ? N : M);
    convert_kernel<<<(N + M + 3) / 4, 256, 0, stream>>>(real, gen, realP, genP, rn, gn,
                                                        realKey, genKey, out, N, M);
    dim3 g((mx + BJ - 1) / BJ, SLICES, 2);
    nn_kernel<<<g, 256, 0, stream>>>(realP, genP, rn, realKey, genKey, N, M);
    finalize_kernel<<<(M + 255) / 256, 256, 0, stream>>>(realKey, genKey, rn, gn, out, M);
}